// Round 9
// baseline (650.156 us; speedup 1.0000x reference)
//
#include <hip/hip_runtime.h>
#include <math.h>

// approxmatch EMD (Fan et al.) — b=8, n=m=2048, f32.
// R9: B-pass eliminated. Fat row kernels emit per-block column partials
// sigma_j = sum_i f'_i * e1_ij using the SAME e1 as the C/A sweep, with
// log2(f') folded into the exponent. Partials merged in LDS (ds_add,
// staggered waves), written plainly to global (NO global atomics); thin
// kernel reduces partials -> (c_j, remR') packed float2.
// Schedule (22 dispatches): prep | A0 | 10 x { thin_t ; CA_t / C9 }.
//   A: f_i = remL_i/(1e-9 + sum_j e(kk) R_j)
//   B: s_j = sum_i f_i e(kk); colsum=R s; rr=min(R/(1e-9+colsum),1); c=R rr;
//      R' = max(R - colsum rr, 0)            [thin, from sigma partials]
//   C: t_i=sum_j c e; u_i=sum_j c e sqrt(d2); remL'=max(remL-f t,0); cost+=f u
// CA_t (t<8): kp = kk_{t+1}; C-weight = e1^4 (level_t = 4*level_{t+1} exact);
// A-part e1; sweep2 sigma_{t+1} = sum 2^(t1 + log2 f').
// Folded exponent: kk*d2 = kk|p|^2 + kk|q|^2 - 2kk(p.q);
// sqrt(d2) = sqrt(|kk*d2|)/sqrt(|kk|) hoisted. Row pairs packed as float2
// (v_pk_fma_f32); exp/sqrt remain scalar (no packed trans pipe).

#define NPTS 2048
#define BLOCK 256
#define RPB 16               // rows per block -> 128 blocks/batch, grid 1024
#define L2E 1.4426950408889634f

typedef float v2 __attribute__((ext_vector_type(2)));

__device__ __forceinline__ float fexp2(float x) { return __builtin_amdgcn_exp2f(x); }
__device__ __forceinline__ float fsqrt(float x) { return __builtin_amdgcn_sqrtf(x); }
__device__ __forceinline__ v2 fma2(v2 a, v2 b, v2 c) { return __builtin_elementwise_fma(a, b, c); }
__device__ __forceinline__ v2 sp(float a) { v2 r; r.x = a; r.y = a; return r; }
__device__ __forceinline__ float xreduce(float v) {
#pragma unroll
    for (int off = 1; off < 64; off <<= 1) v += __shfl_xor(v, off, 64);
    return v;
}

// Pack points as (x,y,z,|p|^2); zero out[].
__global__ void k_prep(const float* __restrict__ xyz1, const float* __restrict__ xyz2,
                       float4* __restrict__ S1, float4* __restrict__ S2,
                       float* __restrict__ out, int bn, int bm, int nout) {
    int i = blockIdx.x * BLOCK + threadIdx.x;
    if (i < bn) {
        const float* p = xyz1 + 3 * (size_t)i;
        float x = p[0], y = p[1], z = p[2];
        S1[i] = make_float4(x, y, z, x*x + y*y + z*z);
    }
    if (i < bm) {
        const float* p = xyz2 + 3 * (size_t)i;
        float x = p[0], y = p[1], z = p[2];
        S2[i] = make_float4(x, y, z, x*x + y*y + z*z);
    }
    if (i < nout) out[i] = 0.f;
}

// Level-0 rows pass: f_0 + sigma_0 partials. LDS 32KB.
__global__ __launch_bounds__(BLOCK) void k_A0(
    const float4* __restrict__ S1, const float4* __restrict__ S2,
    float* __restrict__ f_g, float* __restrict__ sigP,
    float kp, float multiL, float multiR)
{
    __shared__ float sx[NPTS], sy[NPTS], sz[NPTS], ss[NPTS];
    const int row0 = blockIdx.x * RPB;
    const int batch = row0 >> 11;
    const size_t bb = (size_t)batch << 11;
    for (int j = threadIdx.x; j < NPTS; j += BLOCK) {
        float4 q = S2[bb + j];
        sx[j] = q.x; sy[j] = q.y; sz[j] = q.z;
    }
    __syncthreads();
    const int lane = threadIdx.x & 63;
    const int wave = threadIdx.x >> 6;
    const int r0 = row0 + wave * 4;
    v2 paA, paB, pxA, pxB, pyA, pyB, pzA, pzB;
    {
        float4 p0 = S1[r0], p1 = S1[r0+1], p2 = S1[r0+2], p3 = S1[r0+3];
        paA = v2{kp*p0.w, kp*p1.w};    paB = v2{kp*p2.w, kp*p3.w};
        pxA = v2{-2.f*kp*p0.x, -2.f*kp*p1.x}; pxB = v2{-2.f*kp*p2.x, -2.f*kp*p3.x};
        pyA = v2{-2.f*kp*p0.y, -2.f*kp*p1.y}; pyB = v2{-2.f*kp*p2.y, -2.f*kp*p3.y};
        pzA = v2{-2.f*kp*p0.z, -2.f*kp*p1.z}; pzB = v2{-2.f*kp*p2.z, -2.f*kp*p3.z};
    }
    v2 aSA = sp(0.f), aSB = sp(0.f);
#pragma unroll 4
    for (int j = lane; j < NPTS; j += 64) {
        float qx = sx[j], qy = sy[j], qz = sz[j];
        float qb = kp * fmaf(qx, qx, fmaf(qy, qy, qz * qz));
        v2 tA = fma2(pxA, sp(qx), fma2(pyA, sp(qy), fma2(pzA, sp(qz), paA + sp(qb))));
        v2 tB = fma2(pxB, sp(qx), fma2(pyB, sp(qy), fma2(pzB, sp(qz), paB + sp(qb))));
        aSA += v2{fexp2(tA.x), fexp2(tA.y)};
        aSB += v2{fexp2(tB.x), fexp2(tB.y)};
    }
    float fp[4];
    {
        float s0 = xreduce(aSA.x), s1 = xreduce(aSA.y);
        float s2 = xreduce(aSB.x), s3 = xreduce(aSB.y);
        fp[0] = multiL / (1e-9f + multiR * s0);
        fp[1] = multiL / (1e-9f + multiR * s1);
        fp[2] = multiL / (1e-9f + multiR * s2);
        fp[3] = multiL / (1e-9f + multiR * s3);
        if (lane == 0) {
#pragma unroll
            for (int r = 0; r < 4; ++r) f_g[r0 + r] = fp[r];
        }
    }
    v2 qaA = paA + v2{__log2f(fp[0]), __log2f(fp[1])};
    v2 qaB = paB + v2{__log2f(fp[2]), __log2f(fp[3])};
    for (int j = threadIdx.x; j < NPTS; j += BLOCK) ss[j] = 0.f;
    __syncthreads();
#pragma unroll 4
    for (int it = 0; it < NPTS / 64; ++it) {
        int j = (wave * 512 + it * 64 + lane) & 2047;
        float qx = sx[j], qy = sy[j], qz = sz[j];
        float qb = kp * fmaf(qx, qx, fmaf(qy, qy, qz * qz));
        v2 tA = fma2(pxA, sp(qx), fma2(pyA, sp(qy), fma2(pzA, sp(qz), qaA + sp(qb))));
        v2 tB = fma2(pxB, sp(qx), fma2(pyB, sp(qy), fma2(pzB, sp(qz), qaB + sp(qb))));
        float s = (fexp2(tA.x) + fexp2(tA.y)) + (fexp2(tB.x) + fexp2(tB.y));
        atomicAdd(&ss[j], s);
    }
    __syncthreads();
    float* P = sigP + ((size_t)blockIdx.x << 11);
    for (int j = threadIdx.x; j < NPTS; j += BLOCK) P[j] = ss[j];
}

// Thin column finish: sigma -> (c, remR') packed float2.
template <bool FIRST>
__global__ void k_thin(const float* __restrict__ sigP, v2* __restrict__ cr,
                       float multiR, int blksPerBatch)
{
    int gj = blockIdx.x * BLOCK + threadIdx.x;       // 0..16383
    int batch = gj >> 11, j = gj & 2047;
    const float* P = sigP + (((size_t)batch * blksPerBatch) << 11) + j;
    float s = 0.f;
#pragma unroll 8
    for (int k = 0; k < 128; ++k) s += P[(size_t)k << 11];
    float R = FIRST ? multiR : cr[gj].y;
    float colsum = R * s;
    float rr = fminf(R / (1e-9f + colsum), 1.0f);
    v2 o; o.x = R * rr; o.y = fmaxf(R - colsum * rr, 0.f);
    cr[gj] = o;
}

// Fat rows pass: C_t + A_{t+1} + sigma_{t+1} partials. LDS 40960B (4/CU).
// MODE 1 (t<8): kp=kk_{t+1}; C-weight e1^4; aA += rw*e1; sweep2 full.
// MODE 2 (t=8): kp=kk_8; C-weight e1; aA += rw; sigma_9 = block const.
template <int MODE, bool FIRSTC>
__global__ __launch_bounds__(BLOCK) void k_CA(
    const float4* __restrict__ S1, const float4* __restrict__ S2,
    float* __restrict__ f_g, const v2* __restrict__ cr,
    float* __restrict__ remL, float* __restrict__ costrow,
    float* __restrict__ sigP, float kp, float rsqkp, float multiL)
{
    __shared__ float sx[NPTS], sy[NPTS], sz[NPTS];
    __shared__ float scr[2 * NPTS];                  // (c,r) pairs; later sigma
    const int row0 = blockIdx.x * RPB;
    const int batch = row0 >> 11;
    const size_t bb = (size_t)batch << 11;
    for (int j = threadIdx.x; j < NPTS; j += BLOCK) {
        float4 q = S2[bb + j];
        sx[j] = q.x; sy[j] = q.y; sz[j] = q.z;
        *(v2*)&scr[2 * j] = cr[bb + j];
    }
    __syncthreads();
    const int lane = threadIdx.x & 63;
    const int wave = threadIdx.x >> 6;
    const int r0 = row0 + wave * 4;
    v2 paA, paB, pxA, pxB, pyA, pyB, pzA, pzB, fiA, fiB;
    {
        float4 p0 = S1[r0], p1 = S1[r0+1], p2 = S1[r0+2], p3 = S1[r0+3];
        paA = v2{kp*p0.w, kp*p1.w};    paB = v2{kp*p2.w, kp*p3.w};
        pxA = v2{-2.f*kp*p0.x, -2.f*kp*p1.x}; pxB = v2{-2.f*kp*p2.x, -2.f*kp*p3.x};
        pyA = v2{-2.f*kp*p0.y, -2.f*kp*p1.y}; pyB = v2{-2.f*kp*p2.y, -2.f*kp*p3.y};
        pzA = v2{-2.f*kp*p0.z, -2.f*kp*p1.z}; pzB = v2{-2.f*kp*p2.z, -2.f*kp*p3.z};
        fiA = v2{f_g[r0], f_g[r0+1]}; fiB = v2{f_g[r0+2], f_g[r0+3]};
    }
    v2 aTA = sp(0.f), aTB = sp(0.f), aUA = sp(0.f), aUB = sp(0.f);
    v2 aAA = sp(0.f), aAB = sp(0.f);
#pragma unroll 4
    for (int j = lane; j < NPTS; j += 64) {
        float qx = sx[j], qy = sy[j], qz = sz[j];
        v2 crj = *(const v2*)&scr[2 * j];             // cw=.x rw=.y
        float qb = kp * fmaf(qx, qx, fmaf(qy, qy, qz * qz));
        v2 tA = fma2(pxA, sp(qx), fma2(pyA, sp(qy), fma2(pzA, sp(qz), paA + sp(qb))));
        v2 tB = fma2(pxB, sp(qx), fma2(pyB, sp(qy), fma2(pzB, sp(qz), paB + sp(qb))));
        v2 eA = v2{fexp2(tA.x), fexp2(tA.y)};
        v2 eB = v2{fexp2(tB.x), fexp2(tB.y)};
        v2 eCA, eCB;
        if (MODE == 1) { v2 e2A = eA*eA, e2B = eB*eB; eCA = sp(crj.x)*(e2A*e2A); eCB = sp(crj.x)*(e2B*e2B); }
        else           { eCA = sp(crj.x)*eA; eCB = sp(crj.x)*eB; }
        aTA += eCA; aTB += eCB;
        v2 stA = v2{fsqrt(fabsf(tA.x)), fsqrt(fabsf(tA.y))};
        v2 stB = v2{fsqrt(fabsf(tB.x)), fsqrt(fabsf(tB.y))};
        aUA = fma2(eCA, stA, aUA); aUB = fma2(eCB, stB, aUB);
        if (MODE == 1) { aAA = fma2(sp(crj.y), eA, aAA); aAB = fma2(sp(crj.y), eB, aAB); }
        else           { aAA += sp(crj.y); }
    }
    float fp[4];
    {
        float tt[4] = {xreduce(aTA.x), xreduce(aTA.y), xreduce(aTB.x), xreduce(aTB.y)};
        float uu[4] = {xreduce(aUA.x), xreduce(aUA.y), xreduce(aUB.x), xreduce(aUB.y)};
        float aa0 = xreduce(aAA.x), aa1 = xreduce(aAA.y);
        float aa2, aa3;
        if (MODE == 1) { aa2 = xreduce(aAB.x); aa3 = xreduce(aAB.y); }
        else           { aa2 = aa0; aa3 = aa1; aa0 = aa0; }   // MODE2: aAA holds rw-sums (dup rows)
        float aav[4];
        if (MODE == 1) { aav[0]=aa0; aav[1]=aa1; aav[2]=aa2; aav[3]=aa3; }
        else           { aav[0]=aa0; aav[1]=aa0; aav[2]=aa0; aav[3]=aa0; }
        float fiv[4] = {fiA.x, fiA.y, fiB.x, fiB.y};
#pragma unroll
        for (int r = 0; r < 4; ++r) {
            int gi = r0 + r;
            float rl0 = FIRSTC ? multiL : remL[gi];
            float rl = fmaxf(rl0 - fiv[r] * tt[r], 0.f);
            fp[r] = rl / (1e-9f + aav[r]);
            if (lane == 0) {
                costrow[gi] = (FIRSTC ? 0.f : costrow[gi]) + fiv[r] * uu[r] * rsqkp;
                remL[gi] = rl;
                f_g[gi] = fp[r];
            }
        }
    }
    __syncthreads();
    for (int j = threadIdx.x; j < NPTS; j += BLOCK) scr[j] = 0.f;
    __syncthreads();
    float* P = sigP + ((size_t)blockIdx.x << 11);
    if (MODE == 1) {
        v2 qaA = paA + v2{__log2f(fp[0]), __log2f(fp[1])};
        v2 qaB = paB + v2{__log2f(fp[2]), __log2f(fp[3])};
#pragma unroll 4
        for (int it = 0; it < NPTS / 64; ++it) {
            int j = (wave * 512 + it * 64 + lane) & 2047;
            float qx = sx[j], qy = sy[j], qz = sz[j];
            float qb = kp * fmaf(qx, qx, fmaf(qy, qy, qz * qz));
            v2 tA = fma2(pxA, sp(qx), fma2(pyA, sp(qy), fma2(pzA, sp(qz), qaA + sp(qb))));
            v2 tB = fma2(pxB, sp(qx), fma2(pyB, sp(qy), fma2(pzB, sp(qz), qaB + sp(qb))));
            float s = (fexp2(tA.x) + fexp2(tA.y)) + (fexp2(tB.x) + fexp2(tB.y));
            atomicAdd(&scr[j], s);
        }
        __syncthreads();
        for (int j = threadIdx.x; j < NPTS; j += BLOCK) P[j] = scr[j];
    } else {
        if (lane == 0) atomicAdd(&scr[0], ((fp[0] + fp[1]) + (fp[2] + fp[3])));
        __syncthreads();
        float s0 = scr[0];
        for (int j = threadIdx.x; j < NPTS; j += BLOCK) P[j] = s0;
    }
}

// Final level (kk=0): out[batch] += costrow_i + f_i * sum_j c_j sqrt(d2).
__global__ __launch_bounds__(BLOCK) void k_C9(
    const float4* __restrict__ S1, const float4* __restrict__ S2,
    const float* __restrict__ f_g, const v2* __restrict__ cr,
    const float* __restrict__ costrow, float* __restrict__ out)
{
    __shared__ float sx[NPTS], sy[NPTS], sz[NPTS], sc[NPTS];
    __shared__ float wsum[4];
    const int row0 = blockIdx.x * RPB;
    const int batch = row0 >> 11;
    const size_t bb = (size_t)batch << 11;
    for (int j = threadIdx.x; j < NPTS; j += BLOCK) {
        float4 q = S2[bb + j];
        sx[j] = q.x; sy[j] = q.y; sz[j] = q.z; sc[j] = cr[bb + j].x;
    }
    __syncthreads();
    const int lane = threadIdx.x & 63;
    const int wave = threadIdx.x >> 6;
    const int r0 = row0 + wave * 4;
    float px[4], py[4], pz[4], aU[4];
#pragma unroll
    for (int r = 0; r < 4; ++r) {
        float4 p = S1[r0 + r];
        px[r] = p.x; py[r] = p.y; pz[r] = p.z; aU[r] = 0.f;
    }
#pragma unroll 4
    for (int j = lane; j < NPTS; j += 64) {
        float qx = sx[j], qy = sy[j], qz = sz[j], cw = sc[j];
#pragma unroll
        for (int r = 0; r < 4; ++r) {
            float dx = px[r]-qx, dy = py[r]-qy, dz = pz[r]-qz;
            float d2 = fmaf(dx, dx, fmaf(dy, dy, dz * dz));
            aU[r] = fmaf(cw, fsqrt(d2), aU[r]);
        }
    }
    float psum = 0.f;
#pragma unroll
    for (int r = 0; r < 4; ++r) {
        float uu = xreduce(aU[r]);
        if (lane == 0) psum += costrow[r0 + r] + f_g[r0 + r] * uu;
    }
    if (lane == 0) wsum[wave] = psum;
    __syncthreads();
    if (threadIdx.x == 0)
        atomicAdd(&out[batch], (wsum[0] + wsum[1]) + (wsum[2] + wsum[3]));
}

extern "C" void kernel_launch(void* const* d_in, const int* in_sizes, int n_in,
                              void* d_out, int out_size, void* d_ws, size_t ws_size,
                              hipStream_t stream) {
    const float* xyz1 = (const float*)d_in[0];
    const float* xyz2 = (const float*)d_in[1];
    float* out = (float*)d_out;
    const int b = out_size;                 // 8
    const int n = in_sizes[0] / (3 * b);    // 2048
    const int m = in_sizes[1] / (3 * b);    // 2048
    const int bn = b * n, bm = b * m;
    const int blksPerBatch = n / RPB;       // 128

    float4* S1 = (float4*)d_ws;             // bn
    float4* S2 = S1 + bn;                   // bm
    float* f       = (float*)(S2 + bm);     // bn
    float* remL    = f + bn;                // bn
    float* costrow = remL + bn;             // bn
    v2*    cr      = (v2*)(costrow + bn);   // bm float2
    float* sigP    = (float*)(cr + bm);     // (bn/RPB)*2048 floats = 8MB

    const float multiL = (float)((m / n > 1) ? (m / n) : 1);
    const float multiR = (float)((n / m > 1) ? (n / m) : 1);

    dim3 blk(BLOCK);
    dim3 gFat(bn / RPB);                    // 1024
    dim3 gThin(bm / BLOCK);                 // 64
    const int prepN = (bn > bm ? bn : bm);
    k_prep<<<dim3((prepN + BLOCK - 1) / BLOCK), blk, 0, stream>>>(
        xyz1, xyz2, S1, S2, out, bn, bm, b);

    const float kk0 = -16384.f * L2E;       // level -4^7
    k_A0<<<gFat, blk, 0, stream>>>(S1, S2, f, sigP, kk0, multiL, multiR);

    for (int t = 0; t < 10; ++t) {
        if (t == 0) k_thin<true><<<gThin, blk, 0, stream>>>(sigP, cr, multiR, blksPerBatch);
        else        k_thin<false><<<gThin, blk, 0, stream>>>(sigP, cr, multiR, blksPerBatch);

        if (t < 8) {
            const float kk = -exp2f(2.f * (float)(7 - t)) * L2E;   // kk_t
            const float kp = kk * 0.25f;                           // kk_{t+1}
            const float rsq = 1.f / sqrtf(-kp);
            if (t == 0)
                k_CA<1, true><<<gFat, blk, 0, stream>>>(S1, S2, f, cr, remL,
                                                        costrow, sigP, kp, rsq, multiL);
            else
                k_CA<1, false><<<gFat, blk, 0, stream>>>(S1, S2, f, cr, remL,
                                                         costrow, sigP, kp, rsq, multiL);
        } else if (t == 8) {
            const float kp = -0.25f * L2E;                         // kk_8
            const float rsq = 1.f / sqrtf(0.25f * L2E);
            k_CA<2, false><<<gFat, blk, 0, stream>>>(S1, S2, f, cr, remL,
                                                     costrow, sigP, kp, rsq, multiL);
        } else {
            k_C9<<<gFat, blk, 0, stream>>>(S1, S2, f, cr, costrow, out);
        }
    }
}

// Round 10
// 285.706 us; speedup vs baseline: 2.2756x; 2.2756x over previous
//
#include <hip/hip_runtime.h>
#include <math.h>

// approxmatch EMD (Fan et al.) — b=8, n=m=2048, f32.
// R10 = R5 structure (best verified) + v2 row-pair packing (v_pk_fma_f32).
// 22 dispatches: A0(+pack) | 10 x { B_t ; CA_t } | cost. NO sigma fusion.
// Level t: kk_t = -4^(7-t)*L2E (t<=8), kk_9 = 0.
//   A: f_i = multiL/(1e-9 + multiR*sum_j e(kk))          [level 0]
//   B: s_j = sum_i f_i e(kk); colsum=R s; rr=min(R/(1e-9+colsum),1);
//      c=R rr; R' = max(R-colsum rr,0)
//   C: t_i=sum_j c e; u_i=sum_j c e sqrt(d2);
//      remL'=max(remL-f t,0); cost+=f u
// CA_t fuses C_t with A_{t+1} (level_t = 4*level_{t+1} exact for t<8):
// e1=exp2(kk_{t+1} d2) serves C (e1^4) and A (e1).
// Folded exponent: kk*d2 = kk|p|^2 + kk|q|^2 - 2kk(p.q);
// sqrt(d2)=sqrt(|kk d2|)/sqrt(|kk|) hoisted. Rows packed in pairs (v2).

#define NPTS 2048
#define BLOCK 256
#define RPB 16               // rows per block -> 128 blocks/batch, grid 1024
#define L2E 1.4426950408889634f

typedef float v2 __attribute__((ext_vector_type(2)));

__device__ __forceinline__ float fexp2(float x) { return __builtin_amdgcn_exp2f(x); }
__device__ __forceinline__ float fsqrt(float x) { return __builtin_amdgcn_sqrtf(x); }
__device__ __forceinline__ v2 fma2(v2 a, v2 b, v2 c) { return __builtin_elementwise_fma(a, b, c); }
__device__ __forceinline__ v2 sp(float a) { v2 r; r.x = a; r.y = a; return r; }
__device__ __forceinline__ float xreduce(float v) {
#pragma unroll
    for (int off = 1; off < 64; off <<= 1) v += __shfl_xor(v, off, 64);
    return v;
}

// Row-pair state loaded from packed float4 points, scaled by kp.
struct RowPair {
    v2 pa, px, py, pz;
};
__device__ __forceinline__ RowPair mk_pair(float4 a, float4 b, float kp) {
    RowPair r;
    r.pa = v2{kp * a.w, kp * b.w};
    r.px = v2{-2.f*kp*a.x, -2.f*kp*b.x};
    r.py = v2{-2.f*kp*a.y, -2.f*kp*b.y};
    r.pz = v2{-2.f*kp*a.z, -2.f*kp*b.z};
    return r;
}
__device__ __forceinline__ v2 term(const RowPair& r, float qx, float qy, float qz, v2 qb2) {
    return fma2(r.px, sp(qx), fma2(r.py, sp(qy), fma2(r.pz, sp(qz), r.pa + qb2)));
}

// Level-0 rows pass; packs this block's 16 rows/cols into float4 arrays.
__global__ __launch_bounds__(BLOCK) void k_A(
    const float* __restrict__ xyz1, const float* __restrict__ xyz2,
    float4* __restrict__ p1w, float4* __restrict__ p2w,
    float* __restrict__ f_g, float kk, float multiL, float multiR)
{
    __shared__ float sx[NPTS], sy[NPTS], sz[NPTS], sb[NPTS];
    const int row0 = blockIdx.x * RPB;
    const int batch = row0 >> 11;
    const int rloc = row0 & 2047;
    const float* g1 = xyz1 + (size_t)batch * NPTS * 3;
    const float* g2 = xyz2 + (size_t)batch * NPTS * 3;
    if (threadIdx.x < RPB) {
        int i = rloc + threadIdx.x;
        p1w[((size_t)batch << 11) + i] = make_float4(g1[3*i], g1[3*i+1], g1[3*i+2], 0.f);
    } else if (threadIdx.x < 2 * RPB) {
        int i = rloc + threadIdx.x - RPB;
        p2w[((size_t)batch << 11) + i] = make_float4(g2[3*i], g2[3*i+1], g2[3*i+2], 0.f);
    }
    for (int j = threadIdx.x; j < NPTS; j += BLOCK) {
        float qx = g2[3*j], qy = g2[3*j+1], qz = g2[3*j+2];
        sx[j] = qx; sy[j] = qy; sz[j] = qz;
        sb[j] = kk * (qx*qx + qy*qy + qz*qz);
    }
    __syncthreads();
    const int lane = threadIdx.x & 63;
    const int wave = threadIdx.x >> 6;
    const int r0 = row0 + wave * 4;
    RowPair rA, rB;
    {
        const float* p = g1 + 3 * ((r0 & 2047));
        float4 p0 = make_float4(p[0], p[1], p[2], p[0]*p[0]+p[1]*p[1]+p[2]*p[2]);
        float4 p1 = make_float4(p[3], p[4], p[5], p[3]*p[3]+p[4]*p[4]+p[5]*p[5]);
        float4 p2 = make_float4(p[6], p[7], p[8], p[6]*p[6]+p[7]*p[7]+p[8]*p[8]);
        float4 p3 = make_float4(p[9], p[10], p[11], p[9]*p[9]+p[10]*p[10]+p[11]*p[11]);
        rA = mk_pair(p0, p1, kk); rB = mk_pair(p2, p3, kk);
    }
    v2 aSA = sp(0.f), aSB = sp(0.f);
#pragma unroll 8
    for (int j = lane; j < NPTS; j += 64) {
        float qx = sx[j], qy = sy[j], qz = sz[j];
        v2 qb2 = sp(sb[j]);
        v2 tA = term(rA, qx, qy, qz, qb2);
        v2 tB = term(rB, qx, qy, qz, qb2);
        aSA += v2{fexp2(tA.x), fexp2(tA.y)};
        aSB += v2{fexp2(tB.x), fexp2(tB.y)};
    }
    float sv[4] = {xreduce(aSA.x), xreduce(aSA.y), xreduce(aSB.x), xreduce(aSB.y)};
    if (lane == 0) {
#pragma unroll
        for (int r = 0; r < 4; ++r)
            f_g[r0 + r] = multiL / (1e-9f + multiR * sv[r]);
    }
}

// Cols pass.
template <bool FIRST>
__global__ __launch_bounds__(BLOCK) void k_B(
    const float4* __restrict__ p1w, const float4* __restrict__ p2w,
    const float* __restrict__ f_g, float* __restrict__ remR,
    float* __restrict__ c_g, float kk, float multiR)
{
    __shared__ float sx[NPTS], sy[NPTS], sz[NPTS], sb[NPTS], sf[NPTS];
    const int col0 = blockIdx.x * RPB;
    const int batch = col0 >> 11;
    const float4* P1 = p1w + ((size_t)batch << 11);
    const float* F = f_g + ((size_t)batch << 11);
    for (int i = threadIdx.x; i < NPTS; i += BLOCK) {
        float4 q = P1[i];
        sx[i] = q.x; sy[i] = q.y; sz[i] = q.z;
        sb[i] = kk * (q.x*q.x + q.y*q.y + q.z*q.z);
        sf[i] = F[i];
    }
    __syncthreads();
    const int lane = threadIdx.x & 63;
    const int wave = threadIdx.x >> 6;
    const int c0 = col0 + wave * 4;
    RowPair rA, rB;
    {
        float4 q0 = p2w[c0], q1 = p2w[c0+1], q2 = p2w[c0+2], q3 = p2w[c0+3];
        q0.w = q0.x*q0.x + q0.y*q0.y + q0.z*q0.z;
        q1.w = q1.x*q1.x + q1.y*q1.y + q1.z*q1.z;
        q2.w = q2.x*q2.x + q2.y*q2.y + q2.z*q2.z;
        q3.w = q3.x*q3.x + q3.y*q3.y + q3.z*q3.z;
        rA = mk_pair(q0, q1, kk); rB = mk_pair(q2, q3, kk);
    }
    v2 aSA = sp(0.f), aSB = sp(0.f);
#pragma unroll 8
    for (int i = lane; i < NPTS; i += 64) {
        float qx = sx[i], qy = sy[i], qz = sz[i];
        v2 qb2 = sp(sb[i]);
        v2 w2 = sp(sf[i]);
        v2 tA = term(rA, qx, qy, qz, qb2);
        v2 tB = term(rB, qx, qy, qz, qb2);
        aSA = fma2(w2, v2{fexp2(tA.x), fexp2(tA.y)}, aSA);
        aSB = fma2(w2, v2{fexp2(tB.x), fexp2(tB.y)}, aSB);
    }
    float sv[4] = {xreduce(aSA.x), xreduce(aSA.y), xreduce(aSB.x), xreduce(aSB.y)};
    if (lane == 0) {
#pragma unroll
        for (int r = 0; r < 4; ++r) {
            int gj = c0 + r;
            float R = FIRST ? multiR : remR[gj];
            float colsum = R * sv[r];
            float rr = fminf(R / (1e-9f + colsum), 1.0f);
            c_g[gj] = R * rr;
            remR[gj] = fmaxf(R - colsum * rr, 0.f);
        }
    }
}

// Rows pass: C_t fused with A_{t+1}.
// MODE 0: t=9 (kk=0): C only, e==1, plain sqrt(d2), no exp.
// MODE 1: t<8: kp=kk_{t+1}; C-weight=e1^4; aA += rw*e1.
// MODE 2: t=8: kp=kk_8; C-weight=e1; aA = sum rw (hoisted).
template <int MODE, bool FIRSTC>
__global__ __launch_bounds__(BLOCK) void k_CA(
    const float4* __restrict__ p1w, const float4* __restrict__ p2w,
    float* __restrict__ f_g, const float* __restrict__ c_g,
    const float* __restrict__ remR, float* __restrict__ remL,
    float* __restrict__ costrow, float kp, float rsqkp, float multiL)
{
    __shared__ float sx[NPTS], sy[NPTS], sz[NPTS], sc[NPTS], sr[NPTS];
    const int row0 = blockIdx.x * RPB;
    const int batch = row0 >> 11;
    const float4* P2 = p2w + ((size_t)batch << 11);
    const float* C = c_g + ((size_t)batch << 11);
    const float* R = remR + ((size_t)batch << 11);
    for (int j = threadIdx.x; j < NPTS; j += BLOCK) {
        float4 q = P2[j];
        sx[j] = q.x; sy[j] = q.y; sz[j] = q.z; sc[j] = C[j];
        if (MODE) sr[j] = R[j];
    }
    __syncthreads();
    const int lane = threadIdx.x & 63;
    const int wave = threadIdx.x >> 6;
    const int r0 = row0 + wave * 4;

    if (MODE == 0) {
        // plain C pass at kk=0: e==1
        float px[4], py[4], pz[4], aU[4];
#pragma unroll
        for (int r = 0; r < 4; ++r) {
            float4 q = p1w[r0 + r];
            px[r] = q.x; py[r] = q.y; pz[r] = q.z; aU[r] = 0.f;
        }
        float aT = 0.f;
#pragma unroll 4
        for (int j = lane; j < NPTS; j += 64) {
            float qx = sx[j], qy = sy[j], qz = sz[j], cw = sc[j];
            aT += cw;
#pragma unroll
            for (int r = 0; r < 4; ++r) {
                float dx = px[r]-qx, dy = py[r]-qy, dz = pz[r]-qz;
                float d2 = fmaf(dx, dx, fmaf(dy, dy, dz * dz));
                aU[r] = fmaf(cw, fsqrt(d2), aU[r]);
            }
        }
        float tt = xreduce(aT);
#pragma unroll
        for (int r = 0; r < 4; ++r) {
            float uu = xreduce(aU[r]);
            if (lane == 0) {
                int gi = r0 + r;
                float fi = f_g[gi];
                remL[gi] = fmaxf(remL[gi] - fi * tt, 0.f);
                costrow[gi] += fi * uu;
            }
        }
        return;
    }

    RowPair rA, rB;
    v2 fiA, fiB;
    {
        float4 p0 = p1w[r0], p1 = p1w[r0+1], p2 = p1w[r0+2], p3 = p1w[r0+3];
        p0.w = p0.x*p0.x + p0.y*p0.y + p0.z*p0.z;
        p1.w = p1.x*p1.x + p1.y*p1.y + p1.z*p1.z;
        p2.w = p2.x*p2.x + p2.y*p2.y + p2.z*p2.z;
        p3.w = p3.x*p3.x + p3.y*p3.y + p3.z*p3.z;
        rA = mk_pair(p0, p1, kp); rB = mk_pair(p2, p3, kp);
        fiA = v2{f_g[r0], f_g[r0+1]}; fiB = v2{f_g[r0+2], f_g[r0+3]};
    }
    v2 aTA = sp(0.f), aTB = sp(0.f), aUA = sp(0.f), aUB = sp(0.f);
    v2 aAA = sp(0.f), aAB = sp(0.f);
    float aAs = 0.f;
#pragma unroll 4
    for (int j = lane; j < NPTS; j += 64) {
        float qx = sx[j], qy = sy[j], qz = sz[j], cw = sc[j], rw = sr[j];
        v2 qb2 = sp(kp * fmaf(qx, qx, fmaf(qy, qy, qz * qz)));
        v2 tA = term(rA, qx, qy, qz, qb2);
        v2 tB = term(rB, qx, qy, qz, qb2);
        v2 eA = v2{fexp2(tA.x), fexp2(tA.y)};
        v2 eB = v2{fexp2(tB.x), fexp2(tB.y)};
        v2 eCA, eCB;
        if (MODE == 1) {
            v2 e2A = eA * eA, e2B = eB * eB;
            eCA = sp(cw) * (e2A * e2A); eCB = sp(cw) * (e2B * e2B);
        } else {
            eCA = sp(cw) * eA; eCB = sp(cw) * eB;
        }
        aTA += eCA; aTB += eCB;
        v2 stA = v2{fsqrt(fabsf(tA.x)), fsqrt(fabsf(tA.y))};
        v2 stB = v2{fsqrt(fabsf(tB.x)), fsqrt(fabsf(tB.y))};
        aUA = fma2(eCA, stA, aUA); aUB = fma2(eCB, stB, aUB);
        if (MODE == 1) { aAA = fma2(sp(rw), eA, aAA); aAB = fma2(sp(rw), eB, aAB); }
        else           { aAs += rw; }
    }
    float aas = (MODE == 2) ? xreduce(aAs) : 0.f;
    float tt[4] = {xreduce(aTA.x), xreduce(aTA.y), xreduce(aTB.x), xreduce(aTB.y)};
    float uu[4] = {xreduce(aUA.x), xreduce(aUA.y), xreduce(aUB.x), xreduce(aUB.y)};
    float aav[4];
    if (MODE == 1) {
        aav[0] = xreduce(aAA.x); aav[1] = xreduce(aAA.y);
        aav[2] = xreduce(aAB.x); aav[3] = xreduce(aAB.y);
    } else {
        aav[0] = aav[1] = aav[2] = aav[3] = aas;
    }
    float fiv[4] = {fiA.x, fiA.y, fiB.x, fiB.y};
    if (lane == 0) {
#pragma unroll
        for (int r = 0; r < 4; ++r) {
            int gi = r0 + r;
            float rl0 = FIRSTC ? multiL : remL[gi];
            float rl = fmaxf(rl0 - fiv[r] * tt[r], 0.f);
            costrow[gi] = (FIRSTC ? 0.f : costrow[gi]) + fiv[r] * uu[r] * rsqkp;
            remL[gi] = rl;
            f_g[gi] = rl / (1e-9f + aav[r]);
        }
    }
}

__global__ void k_cost(const float* __restrict__ costrow,
                       float* __restrict__ out, int n) {
    __shared__ float wsum[BLOCK / 64];
    const float* cr = costrow + (size_t)blockIdx.x * n;
    float s = 0.f;
    for (int i = threadIdx.x; i < n; i += BLOCK) s += cr[i];
    s = xreduce(s);
    int wave = threadIdx.x >> 6, lane = threadIdx.x & 63;
    if (lane == 0) wsum[wave] = s;
    __syncthreads();
    if (threadIdx.x == 0) {
        float t = 0.f;
#pragma unroll
        for (int w = 0; w < BLOCK / 64; ++w) t += wsum[w];
        out[blockIdx.x] = t;
    }
}

extern "C" void kernel_launch(void* const* d_in, const int* in_sizes, int n_in,
                              void* d_out, int out_size, void* d_ws, size_t ws_size,
                              hipStream_t stream) {
    const float* xyz1 = (const float*)d_in[0];
    const float* xyz2 = (const float*)d_in[1];
    float* out = (float*)d_out;
    const int b = out_size;                 // 8
    const int n = in_sizes[0] / (3 * b);    // 2048
    const int m = in_sizes[1] / (3 * b);    // 2048
    const int bn = b * n, bm = b * m;

    float4* p1w = (float4*)d_ws;            // bn
    float4* p2w = p1w + bn;                 // bm
    float* remL    = (float*)(p2w + bm);    // bn
    float* remR    = remL + bn;             // bm
    float* f       = remR + bm;             // bn
    float* c       = f + bn;                // bm
    float* costrow = c + bm;                // bn

    const float multiL = (float)((m / n > 1) ? (m / n) : 1);
    const float multiR = (float)((n / m > 1) ? (n / m) : 1);

    dim3 g(bn / RPB), blk(BLOCK);
    const float kk0 = -16384.f * L2E;       // level -4^7
    k_A<<<g, blk, 0, stream>>>(xyz1, xyz2, p1w, p2w, f, kk0, multiL, multiR);

    for (int t = 0; t < 10; ++t) {
        const float lvl = (t < 9) ? -exp2f(2.f * (float)(7 - t)) : 0.f;  // -4^(7-t)
        const float kk = lvl * L2E;
        if (t == 0)
            k_B<true><<<g, blk, 0, stream>>>(p1w, p2w, f, remR, c, kk, multiR);
        else
            k_B<false><<<g, blk, 0, stream>>>(p1w, p2w, f, remR, c, kk, multiR);

        if (t < 8) {
            const float kp = kk * 0.25f;                 // = kk_{t+1}
            const float rsq = 1.f / sqrtf(-kp);
            if (t == 0)
                k_CA<1, true><<<g, blk, 0, stream>>>(p1w, p2w, f, c, remR, remL,
                                                     costrow, kp, rsq, multiL);
            else
                k_CA<1, false><<<g, blk, 0, stream>>>(p1w, p2w, f, c, remR, remL,
                                                      costrow, kp, rsq, multiL);
        } else if (t == 8) {
            const float kp = -0.25f * L2E;               // kk_8
            const float rsq = 1.f / sqrtf(0.25f * L2E);
            k_CA<2, false><<<g, blk, 0, stream>>>(p1w, p2w, f, c, remR, remL,
                                                  costrow, kp, rsq, multiL);
        } else {
            k_CA<0, false><<<g, blk, 0, stream>>>(p1w, p2w, f, c, remR, remL,
                                                  costrow, 0.f, 1.f, multiL);
        }
    }
    k_cost<<<dim3(b), blk, 0, stream>>>(costrow, out, n);
}

// Round 11
// 280.242 us; speedup vs baseline: 2.3200x; 1.0195x over previous
//
#include <hip/hip_runtime.h>
#include <math.h>

// approxmatch EMD (Fan et al.) — b=8, n=m=2048, f32.
// R11 = R10 (v2 row-pair packing) + wide LDS staging:
//   swept stream = float4(x,y,z, kk*|q|^2) via ds_read_b128
//               + float2(c,r) (CA) / float(f) (B) via ds_read_b64/b32.
// qb is computed once at staging (not per wave per j-iter).
// 22 dispatches: A0(+pack) | 10 x { B_t ; CA_t } | cost.
// Level t: kk_t = -4^(7-t)*L2E (t<=8), kk_9 = 0.
//   A: f_i = multiL/(1e-9 + multiR*sum_j e(kk))          [level 0]
//   B: s_j = sum_i f_i e(kk); colsum=R s; rr=min(R/(1e-9+colsum),1);
//      c=R rr; R' = max(R-colsum rr,0)
//   C: t_i=sum_j c e; u_i=sum_j c e sqrt(d2);
//      remL'=max(remL-f t,0); cost+=f u
// CA_t fuses C_t with A_{t+1} (level_t = 4*level_{t+1} exact for t<8):
// e1=exp2(kk_{t+1} d2) serves C (e1^4) and A (e1).
// Folded exponent: kk*d2 = kk|p|^2 + kk|q|^2 - 2kk(p.q);
// sqrt(d2)=sqrt(|kk d2|)/sqrt(|kk|) hoisted.

#define NPTS 2048
#define BLOCK 256
#define RPB 16               // rows per block -> 128 blocks/batch, grid 1024
#define L2E 1.4426950408889634f

typedef float v2 __attribute__((ext_vector_type(2)));

__device__ __forceinline__ float fexp2(float x) { return __builtin_amdgcn_exp2f(x); }
__device__ __forceinline__ float fsqrt(float x) { return __builtin_amdgcn_sqrtf(x); }
__device__ __forceinline__ v2 fma2(v2 a, v2 b, v2 c) { return __builtin_elementwise_fma(a, b, c); }
__device__ __forceinline__ v2 sp(float a) { v2 r; r.x = a; r.y = a; return r; }
__device__ __forceinline__ float xreduce(float v) {
#pragma unroll
    for (int off = 1; off < 64; off <<= 1) v += __shfl_xor(v, off, 64);
    return v;
}

struct RowPair { v2 pa, px, py, pz; };
__device__ __forceinline__ RowPair mk_pair(float4 a, float4 b, float kp) {
    RowPair r;
    r.pa = v2{kp * a.w, kp * b.w};
    r.px = v2{-2.f*kp*a.x, -2.f*kp*b.x};
    r.py = v2{-2.f*kp*a.y, -2.f*kp*b.y};
    r.pz = v2{-2.f*kp*a.z, -2.f*kp*b.z};
    return r;
}
__device__ __forceinline__ v2 term(const RowPair& r, float qx, float qy, float qz, v2 qb2) {
    return fma2(r.px, sp(qx), fma2(r.py, sp(qy), fma2(r.pz, sp(qz), r.pa + qb2)));
}

// Level-0 rows pass; packs this block's 16 rows/cols into float4 arrays.
__global__ __launch_bounds__(BLOCK) void k_A(
    const float* __restrict__ xyz1, const float* __restrict__ xyz2,
    float4* __restrict__ p1w, float4* __restrict__ p2w,
    float* __restrict__ f_g, float kk, float multiL, float multiR)
{
    __shared__ float4 sQ[NPTS];              // x,y,z, kk*|q|^2
    const int row0 = blockIdx.x * RPB;
    const int batch = row0 >> 11;
    const int rloc = row0 & 2047;
    const float* g1 = xyz1 + (size_t)batch * NPTS * 3;
    const float* g2 = xyz2 + (size_t)batch * NPTS * 3;
    if (threadIdx.x < RPB) {
        int i = rloc + threadIdx.x;
        p1w[((size_t)batch << 11) + i] = make_float4(g1[3*i], g1[3*i+1], g1[3*i+2], 0.f);
    } else if (threadIdx.x < 2 * RPB) {
        int i = rloc + threadIdx.x - RPB;
        p2w[((size_t)batch << 11) + i] = make_float4(g2[3*i], g2[3*i+1], g2[3*i+2], 0.f);
    }
    for (int j = threadIdx.x; j < NPTS; j += BLOCK) {
        float qx = g2[3*j], qy = g2[3*j+1], qz = g2[3*j+2];
        sQ[j] = make_float4(qx, qy, qz, kk * (qx*qx + qy*qy + qz*qz));
    }
    __syncthreads();
    const int lane = threadIdx.x & 63;
    const int wave = threadIdx.x >> 6;
    const int r0 = row0 + wave * 4;
    RowPair rA, rB;
    {
        const float* p = g1 + 3 * (r0 & 2047);
        float4 p0 = make_float4(p[0], p[1], p[2], p[0]*p[0]+p[1]*p[1]+p[2]*p[2]);
        float4 p1 = make_float4(p[3], p[4], p[5], p[3]*p[3]+p[4]*p[4]+p[5]*p[5]);
        float4 p2 = make_float4(p[6], p[7], p[8], p[6]*p[6]+p[7]*p[7]+p[8]*p[8]);
        float4 p3 = make_float4(p[9], p[10], p[11], p[9]*p[9]+p[10]*p[10]+p[11]*p[11]);
        rA = mk_pair(p0, p1, kk); rB = mk_pair(p2, p3, kk);
    }
    v2 aSA = sp(0.f), aSB = sp(0.f);
#pragma unroll 8
    for (int j = lane; j < NPTS; j += 64) {
        float4 q = sQ[j];
        v2 qb2 = sp(q.w);
        v2 tA = term(rA, q.x, q.y, q.z, qb2);
        v2 tB = term(rB, q.x, q.y, q.z, qb2);
        aSA += v2{fexp2(tA.x), fexp2(tA.y)};
        aSB += v2{fexp2(tB.x), fexp2(tB.y)};
    }
    float sv[4] = {xreduce(aSA.x), xreduce(aSA.y), xreduce(aSB.x), xreduce(aSB.y)};
    if (lane == 0) {
#pragma unroll
        for (int r = 0; r < 4; ++r)
            f_g[r0 + r] = multiL / (1e-9f + multiR * sv[r]);
    }
}

// Cols pass. LDS 40KB -> 4 blocks/CU.
template <bool FIRST>
__global__ __launch_bounds__(BLOCK) void k_B(
    const float4* __restrict__ p1w, const float4* __restrict__ p2w,
    const float* __restrict__ f_g, float* __restrict__ remR,
    float* __restrict__ c_g, float kk, float multiR)
{
    __shared__ float4 sQ[NPTS];              // rows: x,y,z, kk*|p|^2
    __shared__ float sF[NPTS];               // f_i
    const int col0 = blockIdx.x * RPB;
    const int batch = col0 >> 11;
    const float4* P1 = p1w + ((size_t)batch << 11);
    const float* F = f_g + ((size_t)batch << 11);
    for (int i = threadIdx.x; i < NPTS; i += BLOCK) {
        float4 q = P1[i];
        q.w = kk * (q.x*q.x + q.y*q.y + q.z*q.z);
        sQ[i] = q;
        sF[i] = F[i];
    }
    __syncthreads();
    const int lane = threadIdx.x & 63;
    const int wave = threadIdx.x >> 6;
    const int c0 = col0 + wave * 4;
    RowPair rA, rB;
    {
        float4 q0 = p2w[c0], q1 = p2w[c0+1], q2 = p2w[c0+2], q3 = p2w[c0+3];
        q0.w = q0.x*q0.x + q0.y*q0.y + q0.z*q0.z;
        q1.w = q1.x*q1.x + q1.y*q1.y + q1.z*q1.z;
        q2.w = q2.x*q2.x + q2.y*q2.y + q2.z*q2.z;
        q3.w = q3.x*q3.x + q3.y*q3.y + q3.z*q3.z;
        rA = mk_pair(q0, q1, kk); rB = mk_pair(q2, q3, kk);
    }
    v2 aSA = sp(0.f), aSB = sp(0.f);
#pragma unroll 8
    for (int i = lane; i < NPTS; i += 64) {
        float4 p = sQ[i];
        v2 qb2 = sp(p.w);
        v2 w2 = sp(sF[i]);
        v2 tA = term(rA, p.x, p.y, p.z, qb2);
        v2 tB = term(rB, p.x, p.y, p.z, qb2);
        aSA = fma2(w2, v2{fexp2(tA.x), fexp2(tA.y)}, aSA);
        aSB = fma2(w2, v2{fexp2(tB.x), fexp2(tB.y)}, aSB);
    }
    float sv[4] = {xreduce(aSA.x), xreduce(aSA.y), xreduce(aSB.x), xreduce(aSB.y)};
    if (lane == 0) {
#pragma unroll
        for (int r = 0; r < 4; ++r) {
            int gj = c0 + r;
            float R = FIRST ? multiR : remR[gj];
            float colsum = R * sv[r];
            float rr = fminf(R / (1e-9f + colsum), 1.0f);
            c_g[gj] = R * rr;
            remR[gj] = fmaxf(R - colsum * rr, 0.f);
        }
    }
}

// Rows pass: C_t fused with A_{t+1}. LDS 48KB -> 3 blocks/CU.
// MODE 0: t=9 (kk=0): C only, e==1, plain sqrt(d2), no exp.
// MODE 1: t<8: kp=kk_{t+1}; C-weight=e1^4; aA += rw*e1.
// MODE 2: t=8: kp=kk_8; C-weight=e1; aA = sum rw (hoisted).
template <int MODE, bool FIRSTC>
__global__ __launch_bounds__(BLOCK) void k_CA(
    const float4* __restrict__ p1w, const float4* __restrict__ p2w,
    float* __restrict__ f_g, const float* __restrict__ c_g,
    const float* __restrict__ remR, float* __restrict__ remL,
    float* __restrict__ costrow, float kp, float rsqkp, float multiL)
{
    __shared__ float4 sQ[NPTS];              // x,y,z, kp*|q|^2
    __shared__ float2 sCR[NPTS];             // c, r
    const int row0 = blockIdx.x * RPB;
    const int batch = row0 >> 11;
    const float4* P2 = p2w + ((size_t)batch << 11);
    const float* C = c_g + ((size_t)batch << 11);
    const float* R = remR + ((size_t)batch << 11);
    for (int j = threadIdx.x; j < NPTS; j += BLOCK) {
        float4 q = P2[j];
        q.w = kp * (q.x*q.x + q.y*q.y + q.z*q.z);
        sQ[j] = q;
        sCR[j] = make_float2(C[j], MODE ? R[j] : 0.f);
    }
    __syncthreads();
    const int lane = threadIdx.x & 63;
    const int wave = threadIdx.x >> 6;
    const int r0 = row0 + wave * 4;

    if (MODE == 0) {
        float px[4], py[4], pz[4], aU[4];
#pragma unroll
        for (int r = 0; r < 4; ++r) {
            float4 q = p1w[r0 + r];
            px[r] = q.x; py[r] = q.y; pz[r] = q.z; aU[r] = 0.f;
        }
        float aT = 0.f;
#pragma unroll 4
        for (int j = lane; j < NPTS; j += 64) {
            float4 q = sQ[j];
            float cw = sCR[j].x;
            aT += cw;
#pragma unroll
            for (int r = 0; r < 4; ++r) {
                float dx = px[r]-q.x, dy = py[r]-q.y, dz = pz[r]-q.z;
                float d2 = fmaf(dx, dx, fmaf(dy, dy, dz * dz));
                aU[r] = fmaf(cw, fsqrt(d2), aU[r]);
            }
        }
        float tt = xreduce(aT);
#pragma unroll
        for (int r = 0; r < 4; ++r) {
            float uu = xreduce(aU[r]);
            if (lane == 0) {
                int gi = r0 + r;
                float fi = f_g[gi];
                remL[gi] = fmaxf(remL[gi] - fi * tt, 0.f);
                costrow[gi] += fi * uu;
            }
        }
        return;
    }

    RowPair rA, rB;
    v2 fiA, fiB;
    {
        float4 p0 = p1w[r0], p1 = p1w[r0+1], p2 = p1w[r0+2], p3 = p1w[r0+3];
        p0.w = p0.x*p0.x + p0.y*p0.y + p0.z*p0.z;
        p1.w = p1.x*p1.x + p1.y*p1.y + p1.z*p1.z;
        p2.w = p2.x*p2.x + p2.y*p2.y + p2.z*p2.z;
        p3.w = p3.x*p3.x + p3.y*p3.y + p3.z*p3.z;
        rA = mk_pair(p0, p1, kp); rB = mk_pair(p2, p3, kp);
        fiA = v2{f_g[r0], f_g[r0+1]}; fiB = v2{f_g[r0+2], f_g[r0+3]};
    }
    v2 aTA = sp(0.f), aTB = sp(0.f), aUA = sp(0.f), aUB = sp(0.f);
    v2 aAA = sp(0.f), aAB = sp(0.f);
    float aAs = 0.f;
#pragma unroll 4
    for (int j = lane; j < NPTS; j += 64) {
        float4 q = sQ[j];
        float2 crj = sCR[j];
        v2 qb2 = sp(q.w);
        float cw = crj.x, rw = crj.y;
        v2 tA = term(rA, q.x, q.y, q.z, qb2);
        v2 tB = term(rB, q.x, q.y, q.z, qb2);
        v2 eA = v2{fexp2(tA.x), fexp2(tA.y)};
        v2 eB = v2{fexp2(tB.x), fexp2(tB.y)};
        v2 eCA, eCB;
        if (MODE == 1) {
            v2 e2A = eA * eA, e2B = eB * eB;
            eCA = sp(cw) * (e2A * e2A); eCB = sp(cw) * (e2B * e2B);
        } else {
            eCA = sp(cw) * eA; eCB = sp(cw) * eB;
        }
        aTA += eCA; aTB += eCB;
        v2 stA = v2{fsqrt(fabsf(tA.x)), fsqrt(fabsf(tA.y))};
        v2 stB = v2{fsqrt(fabsf(tB.x)), fsqrt(fabsf(tB.y))};
        aUA = fma2(eCA, stA, aUA); aUB = fma2(eCB, stB, aUB);
        if (MODE == 1) { aAA = fma2(sp(rw), eA, aAA); aAB = fma2(sp(rw), eB, aAB); }
        else           { aAs += rw; }
    }
    float aas = (MODE == 2) ? xreduce(aAs) : 0.f;
    float tt[4] = {xreduce(aTA.x), xreduce(aTA.y), xreduce(aTB.x), xreduce(aTB.y)};
    float uu[4] = {xreduce(aUA.x), xreduce(aUA.y), xreduce(aUB.x), xreduce(aUB.y)};
    float aav[4];
    if (MODE == 1) {
        aav[0] = xreduce(aAA.x); aav[1] = xreduce(aAA.y);
        aav[2] = xreduce(aAB.x); aav[3] = xreduce(aAB.y);
    } else {
        aav[0] = aav[1] = aav[2] = aav[3] = aas;
    }
    float fiv[4] = {fiA.x, fiA.y, fiB.x, fiB.y};
    if (lane == 0) {
#pragma unroll
        for (int r = 0; r < 4; ++r) {
            int gi = r0 + r;
            float rl0 = FIRSTC ? multiL : remL[gi];
            float rl = fmaxf(rl0 - fiv[r] * tt[r], 0.f);
            costrow[gi] = (FIRSTC ? 0.f : costrow[gi]) + fiv[r] * uu[r] * rsqkp;
            remL[gi] = rl;
            f_g[gi] = rl / (1e-9f + aav[r]);
        }
    }
}

__global__ void k_cost(const float* __restrict__ costrow,
                       float* __restrict__ out, int n) {
    __shared__ float wsum[BLOCK / 64];
    const float* cr = costrow + (size_t)blockIdx.x * n;
    float s = 0.f;
    for (int i = threadIdx.x; i < n; i += BLOCK) s += cr[i];
    s = xreduce(s);
    int wave = threadIdx.x >> 6, lane = threadIdx.x & 63;
    if (lane == 0) wsum[wave] = s;
    __syncthreads();
    if (threadIdx.x == 0) {
        float t = 0.f;
#pragma unroll
        for (int w = 0; w < BLOCK / 64; ++w) t += wsum[w];
        out[blockIdx.x] = t;
    }
}

extern "C" void kernel_launch(void* const* d_in, const int* in_sizes, int n_in,
                              void* d_out, int out_size, void* d_ws, size_t ws_size,
                              hipStream_t stream) {
    const float* xyz1 = (const float*)d_in[0];
    const float* xyz2 = (const float*)d_in[1];
    float* out = (float*)d_out;
    const int b = out_size;                 // 8
    const int n = in_sizes[0] / (3 * b);    // 2048
    const int m = in_sizes[1] / (3 * b);    // 2048
    const int bn = b * n, bm = b * m;

    float4* p1w = (float4*)d_ws;            // bn
    float4* p2w = p1w + bn;                 // bm
    float* remL    = (float*)(p2w + bm);    // bn
    float* remR    = remL + bn;             // bm
    float* f       = remR + bm;             // bn
    float* c       = f + bn;                // bm
    float* costrow = c + bm;                // bn

    const float multiL = (float)((m / n > 1) ? (m / n) : 1);
    const float multiR = (float)((n / m > 1) ? (n / m) : 1);

    dim3 g(bn / RPB), blk(BLOCK);
    const float kk0 = -16384.f * L2E;       // level -4^7
    k_A<<<g, blk, 0, stream>>>(xyz1, xyz2, p1w, p2w, f, kk0, multiL, multiR);

    for (int t = 0; t < 10; ++t) {
        const float lvl = (t < 9) ? -exp2f(2.f * (float)(7 - t)) : 0.f;  // -4^(7-t)
        const float kk = lvl * L2E;
        if (t == 0)
            k_B<true><<<g, blk, 0, stream>>>(p1w, p2w, f, remR, c, kk, multiR);
        else
            k_B<false><<<g, blk, 0, stream>>>(p1w, p2w, f, remR, c, kk, multiR);

        if (t < 8) {
            const float kp = kk * 0.25f;                 // = kk_{t+1}
            const float rsq = 1.f / sqrtf(-kp);
            if (t == 0)
                k_CA<1, true><<<g, blk, 0, stream>>>(p1w, p2w, f, c, remR, remL,
                                                     costrow, kp, rsq, multiL);
            else
                k_CA<1, false><<<g, blk, 0, stream>>>(p1w, p2w, f, c, remR, remL,
                                                      costrow, kp, rsq, multiL);
        } else if (t == 8) {
            const float kp = -0.25f * L2E;               // kk_8
            const float rsq = 1.f / sqrtf(0.25f * L2E);
            k_CA<2, false><<<g, blk, 0, stream>>>(p1w, p2w, f, c, remR, remL,
                                                  costrow, kp, rsq, multiL);
        } else {
            k_CA<0, false><<<g, blk, 0, stream>>>(p1w, p2w, f, c, remR, remL,
                                                  costrow, 0.f, 1.f, multiL);
        }
    }
    k_cost<<<dim3(b), blk, 0, stream>>>(costrow, out, n);
}